// Round 6
// baseline (41.473 us; speedup 1.0000x reference)
//
#include <hip/hip_runtime.h>
#include <hip/hip_bf16.h>

#define B_ROWS 4096
#define DIMN 128
#define N2 8192
// z pre-scaled by sqrt(log2(e)/TEMP) so mfma output is already the exp2 arg
#define SQRT_CEXP 1.6986436f

using f32x4 = __attribute__((ext_vector_type(4))) float;
typedef long i64;
typedef __attribute__((address_space(3))) unsigned lds_u32;
typedef const __attribute__((address_space(1))) unsigned glb_u32;

// Tiled fp8 Z layout: 8-byte chunk index = (R*4 + kk)*64 + g*16 + fr
//   R = row/16, fr = row%16, kk = k-block (32 fp8 each), g = 8-byte sub-slice.
// A wave's MFMA fragment load (lane = g*16+fr) is zt[(R*4+kk)*64 + lane]
// -> 512B contiguous per instruction, perfectly coalesced (global or LDS).

// --- 1. normalize+scale+quantize into tiled layout; positives partials ------
__global__ __launch_bounds__(256) void normpos_k(const float* __restrict__ emb_i,
                                                 const float* __restrict__ emb_j,
                                                 i64* __restrict__ zt,
                                                 float* __restrict__ pospart) {
    const int t = threadIdx.x;
    const int lr = t >> 4;          // local row / pair
    const int s  = t & 15;          // 8-dim slice
    const int p  = blockIdx.x * 16 + lr;
    const float4* ai = (const float4*)(emb_i + (size_t)p * DIMN + s * 8);
    const float4* bj = (const float4*)(emb_j + (size_t)p * DIMN + s * 8);
    float4 a0 = ai[0], a1 = ai[1];
    float4 b0 = bj[0], b1 = bj[1];
    float sa = a0.x*a0.x + a0.y*a0.y + a0.z*a0.z + a0.w*a0.w
             + a1.x*a1.x + a1.y*a1.y + a1.z*a1.z + a1.w*a1.w;
    float sb = b0.x*b0.x + b0.y*b0.y + b0.z*b0.z + b0.w*b0.w
             + b1.x*b1.x + b1.y*b1.y + b1.z*b1.z + b1.w*b1.w;
    float dp = a0.x*b0.x + a0.y*b0.y + a0.z*b0.z + a0.w*b0.w
             + a1.x*b1.x + a1.y*b1.y + a1.z*b1.z + a1.w*b1.w;
    #pragma unroll
    for (int d = 1; d < 16; d <<= 1) {
        sa += __shfl_xor(sa, d);
        sb += __shfl_xor(sb, d);
        dp += __shfl_xor(dp, d);
    }
    float ia = 1.0f / fmaxf(sqrtf(sa), 1e-12f);
    float ib = 1.0f / fmaxf(sqrtf(sb), 1e-12f);
    float fa = ia * SQRT_CEXP, fb = ib * SQRT_CEXP;

    int wa0 = __builtin_amdgcn_cvt_pk_fp8_f32(a0.x * fa, a0.y * fa, 0, false);
    wa0     = __builtin_amdgcn_cvt_pk_fp8_f32(a0.z * fa, a0.w * fa, wa0, true);
    int wa1 = __builtin_amdgcn_cvt_pk_fp8_f32(a1.x * fa, a1.y * fa, 0, false);
    wa1     = __builtin_amdgcn_cvt_pk_fp8_f32(a1.z * fa, a1.w * fa, wa1, true);
    i64 qa = ((i64)(unsigned)wa1 << 32) | (unsigned)wa0;
    int wb0 = __builtin_amdgcn_cvt_pk_fp8_f32(b0.x * fb, b0.y * fb, 0, false);
    wb0     = __builtin_amdgcn_cvt_pk_fp8_f32(b0.z * fb, b0.w * fb, wb0, true);
    int wb1 = __builtin_amdgcn_cvt_pk_fp8_f32(b1.x * fb, b1.y * fb, 0, false);
    wb1     = __builtin_amdgcn_cvt_pk_fp8_f32(b1.z * fb, b1.w * fb, wb1, true);
    i64 qb = ((i64)(unsigned)wb1 << 32) | (unsigned)wb0;

    const int kk = s >> 2, g = s & 3;
    zt[((blockIdx.x * 4 + kk) * 64) + g * 16 + lr] = qa;                 // R = b
    zt[(((256 + blockIdx.x) * 4 + kk) * 64) + g * 16 + lr] = qb;         // R = 256+b

    __shared__ float red[16];
    if (s == 0) red[lr] = dp * ia * ib;
    __syncthreads();
    if (t == 0) {
        float x = 0.f;
        #pragma unroll
        for (int i = 0; i < 16; ++i) x += red[i];
        pospart[blockIdx.x] = x;
    }
}

// --- chunk epilogue: ps[m][j] += sum_n exp2(acc), optional diagonal mask -----
template <bool MASK>
__device__ __forceinline__ void accum_chunk(const f32x4 (&acc)[4][2],
                                            float (&ps)[4][4],
                                            int rb, int colbase, int rq, int fr) {
    #pragma unroll
    for (int m = 0; m < 4; ++m)
        #pragma unroll
        for (int n = 0; n < 2; ++n)
            #pragma unroll
            for (int j = 0; j < 4; ++j) {
                float e = exp2f(acc[m][n][j]);
                if (MASK) {
                    if (rb + m * 16 + rq + j == colbase + n * 16 + fr) e = 0.f;
                }
                ps[m][j] += e;
            }
}

// --- 2. row-panel Gram, LDS-staged B, 2-phase async pipeline -----------------
// 256 blocks x 1024 thr (16 waves, 1 block/CU). Block b: 64-row panel b>>1,
// col half b&1 (4096 cols in 8 chunks of 512). B chunk (64KB) double-buffered
// in LDS via global_load_lds; one vmcnt-drain+barrier per chunk (inside
// __syncthreads). Wave w owns 32 cols of each chunk. A panel lives in VGPRs.
__global__ __launch_bounds__(1024, 4) void gram_k(const i64* __restrict__ zt,
                                                  float* __restrict__ rowpart) {
    __shared__ i64 Bs[2][8192];          // 2 x 64 KB
    const int t = threadIdx.x;
    const int lane = t & 63;
    const int w = t >> 6;                // 0..15
    const int p = blockIdx.x >> 1;       // 64-row panel
    const int h = blockIdx.x & 1;        // col half
    const int rb = p * 64;
    const int fr = lane & 15;
    const int rq = (lane >> 4) * 4;

    // A panel: 64 rows x 128 dims fp8 (8 KB) -> 32 VGPR, same for all waves
    const i64* Ab = zt + (size_t)p * 1024 + lane;
    i64 A[4][4];
    #pragma unroll
    for (int m = 0; m < 4; ++m)
        #pragma unroll
        for (int kk = 0; kk < 4; ++kk)
            A[m][kk] = Ab[(m * 4 + kk) * 64];

    const i64* gB = zt + (size_t)h * 65536;   // this half's B cols (512 KB)

    auto stage = [&](int nb, int c) {
        const i64* gs = gB + (size_t)c * 8192 + t * 2;
        i64* ls = &Bs[nb][t * 2];
        __builtin_amdgcn_global_load_lds((glb_u32*)(gs),        (lds_u32*)(ls),        16, 0, 0);
        __builtin_amdgcn_global_load_lds((glb_u32*)(gs + 2048), (lds_u32*)(ls + 2048), 16, 0, 0);
        __builtin_amdgcn_global_load_lds((glb_u32*)(gs + 4096), (lds_u32*)(ls + 4096), 16, 0, 0);
        __builtin_amdgcn_global_load_lds((glb_u32*)(gs + 6144), (lds_u32*)(ls + 6144), 16, 0, 0);
    };

    float ps[4][4] = {};

    stage(0, 0);
    __syncthreads();                      // vmcnt(0) drain + barrier

    #pragma unroll
    for (int c = 0; c < 8; ++c) {
        if (c < 7) stage((c + 1) & 1, c + 1);   // async, hides under MFMA
        const int buf = c & 1;
        i64 Bf[2][4];
        #pragma unroll
        for (int n = 0; n < 2; ++n)
            #pragma unroll
            for (int kk = 0; kk < 4; ++kk)
                Bf[n][kk] = Bs[buf][((w * 2 + n) * 4 + kk) * 64 + lane];
        f32x4 acc[4][2] = {};
        #pragma unroll
        for (int kk = 0; kk < 4; ++kk)
            #pragma unroll
            for (int m = 0; m < 4; ++m)
                #pragma unroll
                for (int n = 0; n < 2; ++n)
                    acc[m][n] = __builtin_amdgcn_mfma_f32_16x16x32_fp8_fp8(
                        A[m][kk], Bf[n][kk], acc[m][n], 0, 0, 0);
        const int colbase = h * 4096 + c * 512 + w * 32;
        if (colbase < rb + 64 && colbase + 32 > rb)
            accum_chunk<true >(acc, ps, rb, colbase, rq, fr);
        else
            accum_chunk<false>(acc, ps, rb, colbase, rq, fr);
        __syncthreads();                  // drains next-chunk stage + buffer swap
    }

    // 16-lane reduce per row, cross-wave reduce via LDS (reuse Bs[0]), store
    #pragma unroll
    for (int m = 0; m < 4; ++m)
        #pragma unroll
        for (int j = 0; j < 4; ++j) {
            float v = ps[m][j];
            #pragma unroll
            for (int d = 1; d < 16; d <<= 1) v += __shfl_xor(v, d);
            ps[m][j] = v;
        }
    float* red = (float*)&Bs[0][0];       // 16 x 64 floats
    if (fr == 0) {
        #pragma unroll
        for (int m = 0; m < 4; ++m)
            #pragma unroll
            for (int j = 0; j < 4; ++j)
                red[w * 64 + m * 16 + rq + j] = ps[m][j];
    }
    __syncthreads();
    if (t < 64) {
        float ssum = 0.f;
        #pragma unroll
        for (int ww = 0; ww < 16; ++ww) ssum += red[ww * 64 + t];
        rowpart[h * N2 + rb + t] = ssum;
    }
}

// --- 3. finalize: loss = (sum log(denom) - 4*sum(pos)) / (2B*5) --------------
__global__ void finalize_k(const float* __restrict__ rowpart,
                           const float* __restrict__ pospart,
                           float* __restrict__ out) {
    const int t = threadIdx.x;
    float acc = 0.f;
    for (int r = t; r < N2; r += 1024)
        acc += log2f(rowpart[r] + rowpart[N2 + r]);
    acc *= 0.6931471805599453f;
    if (t < 256) acc -= 4.0f * pospart[t];
    #pragma unroll
    for (int m = 32; m; m >>= 1) acc += __shfl_xor(acc, m);
    __shared__ float red[16];
    if ((t & 63) == 0) red[t >> 6] = acc;
    __syncthreads();
    if (t == 0) {
        float x = 0.f;
        #pragma unroll
        for (int i = 0; i < 16; ++i) x += red[i];
        out[0] = x / (float)(2 * B_ROWS * 5);
    }
}

extern "C" void kernel_launch(void* const* d_in, const int* in_sizes, int n_in,
                              void* d_out, int out_size, void* d_ws, size_t ws_size,
                              hipStream_t stream) {
    const float* emb_i = (const float*)d_in[0];
    const float* emb_j = (const float*)d_in[1];
    i64* zt        = (i64*)d_ws;                                   // 1 MB tiled fp8
    float* rowpart = (float*)((char*)d_ws + (size_t)N2 * DIMN);    // 64 KB (2 halves)
    float* pospart = rowpart + 2 * N2;                             // 1 KB

    normpos_k<<<256, 256, 0, stream>>>(emb_i, emb_j, zt, pospart);
    gram_k<<<256, 1024, 0, stream>>>(zt, rowpart);
    finalize_k<<<1, 1024, 0, stream>>>(rowpart, pospart, (float*)d_out);
}

// Round 7
// 33.762 us; speedup vs baseline: 1.2284x; 1.2284x over previous
//
#include <hip/hip_runtime.h>
#include <hip/hip_bf16.h>

#define B_ROWS 4096
#define DIMN 128
#define N2 8192
// z pre-scaled by sqrt(log2(e)/TEMP) so mfma output is already the exp2 arg
#define SQRT_CEXP 1.6986436f

using f32x4 = __attribute__((ext_vector_type(4))) float;
typedef long i64;
typedef __attribute__((address_space(3))) unsigned lds_u32;
typedef const __attribute__((address_space(1))) unsigned glb_u32;

// Tiled fp8 Z layout: 8-byte chunk index = (R*4 + kk)*64 + g*16 + fr
//   R = row/16, fr = row%16, kk = k-block (32 fp8 each), g = 8-byte sub-slice.
// A wave's MFMA fragment load (lane = g*16+fr) is zt[(R*4+kk)*64 + lane]
// -> 512B contiguous per instruction, perfectly coalesced (global or LDS).

// --- 1. normalize+scale+quantize into tiled layout; positives partials ------
__global__ __launch_bounds__(256) void normpos_k(const float* __restrict__ emb_i,
                                                 const float* __restrict__ emb_j,
                                                 i64* __restrict__ zt,
                                                 float* __restrict__ pospart) {
    const int t = threadIdx.x;
    const int lr = t >> 4;          // local row / pair
    const int s  = t & 15;          // 8-dim slice
    const int p  = blockIdx.x * 16 + lr;
    const float4* ai = (const float4*)(emb_i + (size_t)p * DIMN + s * 8);
    const float4* bj = (const float4*)(emb_j + (size_t)p * DIMN + s * 8);
    float4 a0 = ai[0], a1 = ai[1];
    float4 b0 = bj[0], b1 = bj[1];
    float sa = a0.x*a0.x + a0.y*a0.y + a0.z*a0.z + a0.w*a0.w
             + a1.x*a1.x + a1.y*a1.y + a1.z*a1.z + a1.w*a1.w;
    float sb = b0.x*b0.x + b0.y*b0.y + b0.z*b0.z + b0.w*b0.w
             + b1.x*b1.x + b1.y*b1.y + b1.z*b1.z + b1.w*b1.w;
    float dp = a0.x*b0.x + a0.y*b0.y + a0.z*b0.z + a0.w*b0.w
             + a1.x*b1.x + a1.y*b1.y + a1.z*b1.z + a1.w*b1.w;
    #pragma unroll
    for (int d = 1; d < 16; d <<= 1) {
        sa += __shfl_xor(sa, d);
        sb += __shfl_xor(sb, d);
        dp += __shfl_xor(dp, d);
    }
    float ia = __builtin_amdgcn_rsqf(fmaxf(sa, 1e-24f));  // 1/max(||a||,eps)
    float ib = __builtin_amdgcn_rsqf(fmaxf(sb, 1e-24f));
    float fa = ia * SQRT_CEXP, fb = ib * SQRT_CEXP;

    int wa0 = __builtin_amdgcn_cvt_pk_fp8_f32(a0.x * fa, a0.y * fa, 0, false);
    wa0     = __builtin_amdgcn_cvt_pk_fp8_f32(a0.z * fa, a0.w * fa, wa0, true);
    int wa1 = __builtin_amdgcn_cvt_pk_fp8_f32(a1.x * fa, a1.y * fa, 0, false);
    wa1     = __builtin_amdgcn_cvt_pk_fp8_f32(a1.z * fa, a1.w * fa, wa1, true);
    i64 qa = ((i64)(unsigned)wa1 << 32) | (unsigned)wa0;
    int wb0 = __builtin_amdgcn_cvt_pk_fp8_f32(b0.x * fb, b0.y * fb, 0, false);
    wb0     = __builtin_amdgcn_cvt_pk_fp8_f32(b0.z * fb, b0.w * fb, wb0, true);
    int wb1 = __builtin_amdgcn_cvt_pk_fp8_f32(b1.x * fb, b1.y * fb, 0, false);
    wb1     = __builtin_amdgcn_cvt_pk_fp8_f32(b1.z * fb, b1.w * fb, wb1, true);
    i64 qb = ((i64)(unsigned)wb1 << 32) | (unsigned)wb0;

    const int kk = s >> 2, g = s & 3;
    zt[((blockIdx.x * 4 + kk) * 64) + g * 16 + lr] = qa;                 // R = b
    zt[(((256 + blockIdx.x) * 4 + kk) * 64) + g * 16 + lr] = qb;         // R = 256+b

    __shared__ float red[16];
    if (s == 0) red[lr] = dp * ia * ib;
    __syncthreads();
    if (t == 0) {
        float x = 0.f;
        #pragma unroll
        for (int i = 0; i < 16; ++i) x += red[i];
        pospart[blockIdx.x] = x;
    }
}

// --- chunk epilogue: ps[m][j] += sum_n exp2(acc), optional diagonal mask -----
// NATIVE v_exp_f32 (args bounded: |sim|*log2e/T <= ~6, no denorm/ovf risk)
template <bool MASK>
__device__ __forceinline__ void accum_chunk(const f32x4 (&acc)[4][2],
                                            float (&ps)[4][4],
                                            int rb, int colbase, int rq, int fr) {
    #pragma unroll
    for (int m = 0; m < 4; ++m)
        #pragma unroll
        for (int n = 0; n < 2; ++n)
            #pragma unroll
            for (int j = 0; j < 4; ++j) {
                float e = __builtin_amdgcn_exp2f(acc[m][n][j]);
                if (MASK) {
                    if (rb + m * 16 + rq + j == colbase + n * 16 + fr) e = 0.f;
                }
                ps[m][j] += e;
            }
}

// --- 2. row-panel Gram, LDS-staged B, 2-phase async pipeline -----------------
// 256 blocks x 1024 thr (16 waves, 1 block/CU). Block b: 64-row panel b>>1,
// col half b&1 (4096 cols in 8 chunks of 512). B chunk (64KB) double-buffered
// in LDS via global_load_lds; one vmcnt-drain+barrier per chunk (inside
// __syncthreads). Wave w owns 32 cols of each chunk. A panel lives in VGPRs.
__global__ __launch_bounds__(1024, 4) void gram_k(const i64* __restrict__ zt,
                                                  float* __restrict__ rowpart) {
    __shared__ i64 Bs[2][8192];          // 2 x 64 KB
    const int t = threadIdx.x;
    const int lane = t & 63;
    const int w = t >> 6;                // 0..15
    const int p = blockIdx.x >> 1;       // 64-row panel
    const int h = blockIdx.x & 1;        // col half
    const int rb = p * 64;
    const int fr = lane & 15;
    const int rq = (lane >> 4) * 4;

    // A panel: 64 rows x 128 dims fp8 (8 KB) -> 32 VGPR, same for all waves
    const i64* Ab = zt + (size_t)p * 1024 + lane;
    i64 A[4][4];
    #pragma unroll
    for (int m = 0; m < 4; ++m)
        #pragma unroll
        for (int kk = 0; kk < 4; ++kk)
            A[m][kk] = Ab[(m * 4 + kk) * 64];

    const i64* gB = zt + (size_t)h * 65536;   // this half's B cols (512 KB)

    auto stage = [&](int nb, int c) {
        const i64* gs = gB + (size_t)c * 8192 + t * 2;
        i64* ls = &Bs[nb][t * 2];
        __builtin_amdgcn_global_load_lds((glb_u32*)(gs),        (lds_u32*)(ls),        16, 0, 0);
        __builtin_amdgcn_global_load_lds((glb_u32*)(gs + 2048), (lds_u32*)(ls + 2048), 16, 0, 0);
        __builtin_amdgcn_global_load_lds((glb_u32*)(gs + 4096), (lds_u32*)(ls + 4096), 16, 0, 0);
        __builtin_amdgcn_global_load_lds((glb_u32*)(gs + 6144), (lds_u32*)(ls + 6144), 16, 0, 0);
    };

    float ps[4][4] = {};

    stage(0, 0);
    __syncthreads();                      // vmcnt(0) drain + barrier

    #pragma unroll
    for (int c = 0; c < 8; ++c) {
        if (c < 7) stage((c + 1) & 1, c + 1);   // async, hides under MFMA
        const int buf = c & 1;
        i64 Bf[2][4];
        #pragma unroll
        for (int n = 0; n < 2; ++n)
            #pragma unroll
            for (int kk = 0; kk < 4; ++kk)
                Bf[n][kk] = Bs[buf][((w * 2 + n) * 4 + kk) * 64 + lane];
        f32x4 acc[4][2] = {};
        #pragma unroll
        for (int kk = 0; kk < 4; ++kk)
            #pragma unroll
            for (int m = 0; m < 4; ++m)
                #pragma unroll
                for (int n = 0; n < 2; ++n)
                    acc[m][n] = __builtin_amdgcn_mfma_f32_16x16x32_fp8_fp8(
                        A[m][kk], Bf[n][kk], acc[m][n], 0, 0, 0);
        const int colbase = h * 4096 + c * 512 + w * 32;
        if (colbase < rb + 64 && colbase + 32 > rb)
            accum_chunk<true >(acc, ps, rb, colbase, rq, fr);
        else
            accum_chunk<false>(acc, ps, rb, colbase, rq, fr);
        __syncthreads();                  // drains next-chunk stage + buffer swap
    }

    // 16-lane reduce per row, cross-wave reduce via LDS (reuse Bs[0]), store
    #pragma unroll
    for (int m = 0; m < 4; ++m)
        #pragma unroll
        for (int j = 0; j < 4; ++j) {
            float v = ps[m][j];
            #pragma unroll
            for (int d = 1; d < 16; d <<= 1) v += __shfl_xor(v, d);
            ps[m][j] = v;
        }
    float* red = (float*)&Bs[0][0];       // 16 x 64 floats
    if (fr == 0) {
        #pragma unroll
        for (int m = 0; m < 4; ++m)
            #pragma unroll
            for (int j = 0; j < 4; ++j)
                red[w * 64 + m * 16 + rq + j] = ps[m][j];
    }
    __syncthreads();
    if (t < 64) {
        float ssum = 0.f;
        #pragma unroll
        for (int ww = 0; ww < 16; ++ww) ssum += red[ww * 64 + t];
        rowpart[h * N2 + rb + t] = ssum;
    }
}

// --- 3. finalize: loss = (sum log(denom) - 4*sum(pos)) / (2B*5) --------------
__global__ void finalize_k(const float* __restrict__ rowpart,
                           const float* __restrict__ pospart,
                           float* __restrict__ out) {
    const int t = threadIdx.x;
    float acc = 0.f;
    for (int r = t; r < N2; r += 1024)
        acc += __builtin_amdgcn_logf(rowpart[r] + rowpart[N2 + r]);  // log2, native
    acc *= 0.6931471805599453f;                                      // ln2
    if (t < 256) acc -= 4.0f * pospart[t];
    #pragma unroll
    for (int m = 32; m; m >>= 1) acc += __shfl_xor(acc, m);
    __shared__ float red[16];
    if ((t & 63) == 0) red[t >> 6] = acc;
    __syncthreads();
    if (t == 0) {
        float x = 0.f;
        #pragma unroll
        for (int i = 0; i < 16; ++i) x += red[i];
        out[0] = x / (float)(2 * B_ROWS * 5);
    }
}

extern "C" void kernel_launch(void* const* d_in, const int* in_sizes, int n_in,
                              void* d_out, int out_size, void* d_ws, size_t ws_size,
                              hipStream_t stream) {
    const float* emb_i = (const float*)d_in[0];
    const float* emb_j = (const float*)d_in[1];
    i64* zt        = (i64*)d_ws;                                   // 1 MB tiled fp8
    float* rowpart = (float*)((char*)d_ws + (size_t)N2 * DIMN);    // 64 KB (2 halves)
    float* pospart = rowpart + 2 * N2;                             // 1 KB

    normpos_k<<<256, 256, 0, stream>>>(emb_i, emb_j, zt, pospart);
    gram_k<<<256, 1024, 0, stream>>>(zt, rowpart);
    finalize_k<<<1, 1024, 0, stream>>>(rowpart, pospart, (float*)d_out);
}

// Round 8
// 31.012 us; speedup vs baseline: 1.3373x; 1.0887x over previous
//
#include <hip/hip_runtime.h>
#include <hip/hip_bf16.h>

#define B_ROWS 4096
#define DIMN 128
#define N2 8192
// z pre-scaled by sqrt(log2(e)/TEMP) so mfma output is already the exp2 arg
#define SQRT_CEXP 1.6986436f

using f32x4 = __attribute__((ext_vector_type(4))) float;
typedef long i64;
typedef __attribute__((address_space(3))) unsigned lds_u32;
typedef const __attribute__((address_space(1))) unsigned glb_u32;

// Tiled fp8 Z layout: 8-byte chunk index = (R*4 + kk)*64 + g*16 + fr
//   R = row/16, fr = row%16, kk = k-block (32 fp8 each), g = 8-byte sub-slice.
// A wave's MFMA fragment load (lane = g*16+fr) is zt[(R*4+kk)*64 + lane]
// -> 512B contiguous per instruction, perfectly coalesced (global or LDS).

// --- 1. normalize+scale+quantize into tiled layout; positives partials ------
__global__ __launch_bounds__(256) void normpos_k(const float* __restrict__ emb_i,
                                                 const float* __restrict__ emb_j,
                                                 i64* __restrict__ zt,
                                                 float* __restrict__ pospart) {
    const int t = threadIdx.x;
    const int lr = t >> 4;          // local row / pair
    const int s  = t & 15;          // 8-dim slice
    const int p  = blockIdx.x * 16 + lr;
    const float4* ai = (const float4*)(emb_i + (size_t)p * DIMN + s * 8);
    const float4* bj = (const float4*)(emb_j + (size_t)p * DIMN + s * 8);
    float4 a0 = ai[0], a1 = ai[1];
    float4 b0 = bj[0], b1 = bj[1];
    float sa = a0.x*a0.x + a0.y*a0.y + a0.z*a0.z + a0.w*a0.w
             + a1.x*a1.x + a1.y*a1.y + a1.z*a1.z + a1.w*a1.w;
    float sb = b0.x*b0.x + b0.y*b0.y + b0.z*b0.z + b0.w*b0.w
             + b1.x*b1.x + b1.y*b1.y + b1.z*b1.z + b1.w*b1.w;
    float dp = a0.x*b0.x + a0.y*b0.y + a0.z*b0.z + a0.w*b0.w
             + a1.x*b1.x + a1.y*b1.y + a1.z*b1.z + a1.w*b1.w;
    #pragma unroll
    for (int d = 1; d < 16; d <<= 1) {
        sa += __shfl_xor(sa, d);
        sb += __shfl_xor(sb, d);
        dp += __shfl_xor(dp, d);
    }
    float ia = __builtin_amdgcn_rsqf(fmaxf(sa, 1e-24f));
    float ib = __builtin_amdgcn_rsqf(fmaxf(sb, 1e-24f));
    float fa = ia * SQRT_CEXP, fb = ib * SQRT_CEXP;

    int wa0 = __builtin_amdgcn_cvt_pk_fp8_f32(a0.x * fa, a0.y * fa, 0, false);
    wa0     = __builtin_amdgcn_cvt_pk_fp8_f32(a0.z * fa, a0.w * fa, wa0, true);
    int wa1 = __builtin_amdgcn_cvt_pk_fp8_f32(a1.x * fa, a1.y * fa, 0, false);
    wa1     = __builtin_amdgcn_cvt_pk_fp8_f32(a1.z * fa, a1.w * fa, wa1, true);
    i64 qa = ((i64)(unsigned)wa1 << 32) | (unsigned)wa0;
    int wb0 = __builtin_amdgcn_cvt_pk_fp8_f32(b0.x * fb, b0.y * fb, 0, false);
    wb0     = __builtin_amdgcn_cvt_pk_fp8_f32(b0.z * fb, b0.w * fb, wb0, true);
    int wb1 = __builtin_amdgcn_cvt_pk_fp8_f32(b1.x * fb, b1.y * fb, 0, false);
    wb1     = __builtin_amdgcn_cvt_pk_fp8_f32(b1.z * fb, b1.w * fb, wb1, true);
    i64 qb = ((i64)(unsigned)wb1 << 32) | (unsigned)wb0;

    const int kk = s >> 2, g = s & 3;
    zt[((blockIdx.x * 4 + kk) * 64) + g * 16 + lr] = qa;                 // R = b
    zt[(((256 + blockIdx.x) * 4 + kk) * 64) + g * 16 + lr] = qb;         // R = 256+b

    __shared__ float red[16];
    if (s == 0) red[lr] = dp * ia * ib;
    __syncthreads();
    if (t == 0) {
        float x = 0.f;
        #pragma unroll
        for (int i = 0; i < 16; ++i) x += red[i];
        pospart[blockIdx.x] = x;
    }
}

// --- chunk epilogue: ps[m][j] += sum_n exp2(acc), optional diagonal mask -----
template <bool MASK>
__device__ __forceinline__ void accum_chunk(const f32x4 (&acc)[4][2],
                                            float (&ps)[4][4],
                                            int rb, int colbase, int rq, int fr) {
    #pragma unroll
    for (int m = 0; m < 4; ++m)
        #pragma unroll
        for (int n = 0; n < 2; ++n)
            #pragma unroll
            for (int j = 0; j < 4; ++j) {
                float e = __builtin_amdgcn_exp2f(acc[m][n][j]);
                if (MASK) {
                    if (rb + m * 16 + rq + j == colbase + n * 16 + fr) e = 0.f;
                }
                ps[m][j] += e;
            }
}

// --- 2. row-panel Gram, wave-autonomous pipeline (NO barriers in main loop) --
// 512 blocks x 512 thr (8 waves, 2 blocks/CU). Block b: 64-row panel b>>2,
// col quarter b&3 (2048 cols). Wave w: cols q*2048+w*256, 8 chunks of 32.
// Each wave stages ITS OWN next chunk into a private LDS double buffer via
// global_load_lds; counted s_waitcnt vmcnt(4) (never 0 mid-loop); asm
// ds_read_b64 + lgkmcnt(0) + sched_barrier(0) (rule #18); setprio on MFMA.
__global__ __launch_bounds__(512, 4) void gram_k(const i64* __restrict__ zt,
                                                 float* __restrict__ rowpart) {
    __shared__ i64 Bs[8192];             // 8 waves x 2 bufs x 512 i64 = 64 KB
    const int t = threadIdx.x;
    const int lane = t & 63;
    const int w = t >> 6;                // 0..7
    const int p = blockIdx.x >> 2;       // 64-row panel, 0..127
    const int q = blockIdx.x & 3;        // col quarter
    const int rb = p * 64;
    const int fr = lane & 15;
    const int rq = (lane >> 4) * 4;

    // A panel: 64 rows x 128 dims fp8 (8 KB) -> 32 VGPR
    const i64* Ab = zt + (size_t)p * 1024 + lane;
    i64 A[4][4];
    #pragma unroll
    for (int m = 0; m < 4; ++m)
        #pragma unroll
        for (int kk = 0; kk < 4; ++kk)
            A[m][kk] = Ab[(m * 4 + kk) * 64];
    asm volatile("s_waitcnt vmcnt(0)" ::: "memory");   // clean vmcnt baseline

    // wave-private staging
    const i64* gw = zt + ((size_t)q * 128 + w * 16) * 256;  // wave's 256-col region
    i64* ls = Bs + w * 1024;                                // 2 bufs x 512 i64
    auto stage = [&](int buf, int c) {
        const i64* s = gw + c * 512 + lane * 2;
        i64* d = ls + buf * 512 + lane * 2;
        __builtin_amdgcn_global_load_lds((glb_u32*)(s),       (lds_u32*)(d),       16, 0, 0);
        __builtin_amdgcn_global_load_lds((glb_u32*)(s + 128), (lds_u32*)(d + 128), 16, 0, 0);
        __builtin_amdgcn_global_load_lds((glb_u32*)(s + 256), (lds_u32*)(d + 256), 16, 0, 0);
        __builtin_amdgcn_global_load_lds((glb_u32*)(s + 384), (lds_u32*)(d + 384), 16, 0, 0);
    };

    const unsigned lbase = (unsigned)(uintptr_t)(&Bs[0]) + (unsigned)(w * 8192 + lane * 8);
    const unsigned a0 = lbase, a1 = lbase + 4096;

    float ps[4][4] = {};
    stage(0, 0);

    #pragma unroll
    for (int c = 0; c < 8; ++c) {
        if (c < 7) {
            stage((c + 1) & 1, c + 1);                     // prefetch next chunk
            asm volatile("s_waitcnt vmcnt(4)" ::: "memory"); // chunk c staged; c+1 in flight
        } else {
            asm volatile("s_waitcnt vmcnt(0)" ::: "memory");
        }
        __builtin_amdgcn_sched_barrier(0);
        const unsigned a = (c & 1) ? a1 : a0;
        i64 b0, b1, b2, b3, b4, b5, b6, b7;
        asm volatile("ds_read_b64 %0, %1 offset:0"    : "=v"(b0) : "v"(a));
        asm volatile("ds_read_b64 %0, %1 offset:512"  : "=v"(b1) : "v"(a));
        asm volatile("ds_read_b64 %0, %1 offset:1024" : "=v"(b2) : "v"(a));
        asm volatile("ds_read_b64 %0, %1 offset:1536" : "=v"(b3) : "v"(a));
        asm volatile("ds_read_b64 %0, %1 offset:2048" : "=v"(b4) : "v"(a));
        asm volatile("ds_read_b64 %0, %1 offset:2560" : "=v"(b5) : "v"(a));
        asm volatile("ds_read_b64 %0, %1 offset:3072" : "=v"(b6) : "v"(a));
        asm volatile("ds_read_b64 %0, %1 offset:3584" : "=v"(b7) : "v"(a));
        asm volatile("s_waitcnt lgkmcnt(0)" ::: "memory");
        __builtin_amdgcn_sched_barrier(0);                 // rule #18 fence
        i64 Bf[2][4] = {{b0, b1, b2, b3}, {b4, b5, b6, b7}};
        f32x4 acc[4][2] = {};
        __builtin_amdgcn_s_setprio(1);
        #pragma unroll
        for (int kk = 0; kk < 4; ++kk)
            #pragma unroll
            for (int m = 0; m < 4; ++m) {
                acc[m][0] = __builtin_amdgcn_mfma_f32_16x16x32_fp8_fp8(
                    A[m][kk], Bf[0][kk], acc[m][0], 0, 0, 0);
                acc[m][1] = __builtin_amdgcn_mfma_f32_16x16x32_fp8_fp8(
                    A[m][kk], Bf[1][kk], acc[m][1], 0, 0, 0);
            }
        __builtin_amdgcn_s_setprio(0);
        const int cb = q * 2048 + w * 256 + c * 32;
        if (cb == rb || cb == rb + 32)
            accum_chunk<true >(acc, ps, rb, cb, rq, fr);
        else
            accum_chunk<false>(acc, ps, rb, cb, rq, fr);
    }

    // 16-lane reduce per row, then ONE barrier + cross-wave reduce (reuse Bs)
    #pragma unroll
    for (int m = 0; m < 4; ++m)
        #pragma unroll
        for (int j = 0; j < 4; ++j) {
            float v = ps[m][j];
            #pragma unroll
            for (int d = 1; d < 16; d <<= 1) v += __shfl_xor(v, d);
            ps[m][j] = v;
        }
    float* red = (float*)&Bs[0];          // 8 x 64 floats
    __syncthreads();                      // all waves done with their LDS slices
    if (fr == 0) {
        #pragma unroll
        for (int m = 0; m < 4; ++m)
            #pragma unroll
            for (int j = 0; j < 4; ++j)
                red[w * 64 + m * 16 + rq + j] = ps[m][j];
    }
    __syncthreads();
    if (t < 64) {
        float ssum = 0.f;
        #pragma unroll
        for (int ww = 0; ww < 8; ++ww) ssum += red[ww * 64 + t];
        rowpart[q * N2 + rb + t] = ssum;
    }
}

// --- 3. finalize: loss = (sum log(denom) - 4*sum(pos)) / (2B*5) --------------
__global__ void finalize_k(const float* __restrict__ rowpart,
                           const float* __restrict__ pospart,
                           float* __restrict__ out) {
    const int t = threadIdx.x;
    float acc = 0.f;
    for (int r = t; r < N2; r += 1024)
        acc += __builtin_amdgcn_logf(rowpart[r] + rowpart[N2 + r] +
                                     rowpart[2 * N2 + r] + rowpart[3 * N2 + r]);
    acc *= 0.6931471805599453f;                                      // ln2 (log2->ln)
    if (t < 256) acc -= 4.0f * pospart[t];
    #pragma unroll
    for (int m = 32; m; m >>= 1) acc += __shfl_xor(acc, m);
    __shared__ float red[16];
    if ((t & 63) == 0) red[t >> 6] = acc;
    __syncthreads();
    if (t == 0) {
        float x = 0.f;
        #pragma unroll
        for (int i = 0; i < 16; ++i) x += red[i];
        out[0] = x / (float)(2 * B_ROWS * 5);
    }
}

extern "C" void kernel_launch(void* const* d_in, const int* in_sizes, int n_in,
                              void* d_out, int out_size, void* d_ws, size_t ws_size,
                              hipStream_t stream) {
    const float* emb_i = (const float*)d_in[0];
    const float* emb_j = (const float*)d_in[1];
    i64* zt        = (i64*)d_ws;                                   // 1 MB tiled fp8
    float* rowpart = (float*)((char*)d_ws + (size_t)N2 * DIMN);    // 128 KB (4 parts)
    float* pospart = rowpart + 4 * N2;                             // 1 KB

    normpos_k<<<256, 256, 0, stream>>>(emb_i, emb_j, zt, pospart);
    gram_k<<<512, 512, 0, stream>>>(zt, rowpart);
    finalize_k<<<1, 1024, 0, stream>>>(rowpart, pospart, (float*)d_out);
}

// Round 9
// 29.687 us; speedup vs baseline: 1.3970x; 1.0446x over previous
//
#include <hip/hip_runtime.h>
#include <hip/hip_bf16.h>

#define B_ROWS 4096
#define DIMN 128
#define N2 8192
// z pre-scaled by sqrt(log2(e)/TEMP) so mfma output is already the exp2 arg
#define SQRT_CEXP 1.6986436f

using f32x4 = __attribute__((ext_vector_type(4))) float;
using i32x4 = __attribute__((ext_vector_type(4))) int;
using i32x8 = __attribute__((ext_vector_type(8))) int;
typedef long i64;

// f8f6f4-native tiled Z layout:
//   byte addr = Rtile*2048 + lane*32 + b,  lane = (k>>5)*16 + (row&15)
//   i.e. lane l holds k in [32*(l>>4), +32) of row Rtile*16 + (l&15).
// This IS the 16x16x128 MFMA A/B fragment: load = 2x global_load_dwordx4,
// 64 lanes x 32B = 2048B contiguous per tile. A and B use the identical rule,
// so the Gram dot-product is invariant to any k-permutation assumption.

// --- 1. normalize+scale+quantize into fragment layout; positives partials ---
__global__ __launch_bounds__(256) void normpos_k(const float* __restrict__ emb_i,
                                                 const float* __restrict__ emb_j,
                                                 i64* __restrict__ zt,
                                                 float* __restrict__ pospart) {
    const int t = threadIdx.x;
    const int lr = t >> 4;          // local row / pair
    const int s  = t & 15;          // 8-float slice (k = s*8..s*8+7)
    const int p  = blockIdx.x * 16 + lr;
    const float4* ai = (const float4*)(emb_i + (size_t)p * DIMN + s * 8);
    const float4* bj = (const float4*)(emb_j + (size_t)p * DIMN + s * 8);
    float4 a0 = ai[0], a1 = ai[1];
    float4 b0 = bj[0], b1 = bj[1];
    float sa = a0.x*a0.x + a0.y*a0.y + a0.z*a0.z + a0.w*a0.w
             + a1.x*a1.x + a1.y*a1.y + a1.z*a1.z + a1.w*a1.w;
    float sb = b0.x*b0.x + b0.y*b0.y + b0.z*b0.z + b0.w*b0.w
             + b1.x*b1.x + b1.y*b1.y + b1.z*b1.z + b1.w*b1.w;
    float dp = a0.x*b0.x + a0.y*b0.y + a0.z*b0.z + a0.w*b0.w
             + a1.x*b1.x + a1.y*b1.y + a1.z*b1.z + a1.w*b1.w;
    #pragma unroll
    for (int d = 1; d < 16; d <<= 1) {
        sa += __shfl_xor(sa, d);
        sb += __shfl_xor(sb, d);
        dp += __shfl_xor(dp, d);
    }
    float ia = __builtin_amdgcn_rsqf(fmaxf(sa, 1e-24f));
    float ib = __builtin_amdgcn_rsqf(fmaxf(sb, 1e-24f));
    float fa = ia * SQRT_CEXP, fb = ib * SQRT_CEXP;

    int wa0 = __builtin_amdgcn_cvt_pk_fp8_f32(a0.x * fa, a0.y * fa, 0, false);
    wa0     = __builtin_amdgcn_cvt_pk_fp8_f32(a0.z * fa, a0.w * fa, wa0, true);
    int wa1 = __builtin_amdgcn_cvt_pk_fp8_f32(a1.x * fa, a1.y * fa, 0, false);
    wa1     = __builtin_amdgcn_cvt_pk_fp8_f32(a1.z * fa, a1.w * fa, wa1, true);
    i64 qa = ((i64)(unsigned)wa1 << 32) | (unsigned)wa0;
    int wb0 = __builtin_amdgcn_cvt_pk_fp8_f32(b0.x * fb, b0.y * fb, 0, false);
    wb0     = __builtin_amdgcn_cvt_pk_fp8_f32(b0.z * fb, b0.w * fb, wb0, true);
    int wb1 = __builtin_amdgcn_cvt_pk_fp8_f32(b1.x * fb, b1.y * fb, 0, false);
    wb1     = __builtin_amdgcn_cvt_pk_fp8_f32(b1.z * fb, b1.w * fb, wb1, true);
    i64 qb = ((i64)(unsigned)wb1 << 32) | (unsigned)wb0;

    // fragment slot: k-block gk = s>>2, i64-in-lane = s&3, lane = gk*16+lr
    const int slot = ((s >> 2) * 16 + lr) * 4 + (s & 3);
    zt[(size_t)blockIdx.x * 256 + slot] = qa;            // Rtile = b
    zt[(size_t)(256 + blockIdx.x) * 256 + slot] = qb;    // Rtile = 256+b

    __shared__ float red[16];
    if (s == 0) red[lr] = dp * ia * ib;
    __syncthreads();
    if (t == 0) {
        float x = 0.f;
        #pragma unroll
        for (int i = 0; i < 16; ++i) x += red[i];
        pospart[blockIdx.x] = x;
    }
}

// --- step epilogue: ps[m][j] += sum_n exp2(acc), optional diagonal mask ------
template <bool MASK>
__device__ __forceinline__ void accum_step(const f32x4 (&acc)[4][2],
                                           float (&ps)[4][4],
                                           int rb, int colbase, int rq, int fr) {
    #pragma unroll
    for (int m = 0; m < 4; ++m)
        #pragma unroll
        for (int n = 0; n < 2; ++n)
            #pragma unroll
            for (int j = 0; j < 4; ++j) {
                float e = __builtin_amdgcn_exp2f(acc[m][n][j]);
                if (MASK) {
                    if (rb + m * 16 + rq + j == colbase + n * 16 + fr) e = 0.f;
                }
                ps[m][j] += e;
            }
}

// --- 2. row-panel Gram via MX-scaled 16x16x128 MFMA, reg-dbuf pipeline -------
// 1024 blocks x 256 thr (4 waves). Block b: 64-row panel b>>3, col-eighth b&7.
// Wave w: 256 cols at e*1024+w*256, 8 steps of 32 cols (2 tiles). All loads
// inline-asm (no compiler auto-vmcnt); counted vmcnt(4); sched_barrier fence.
__global__ __launch_bounds__(256, 3) void gram_k(const char* __restrict__ zt,
                                                 float* __restrict__ rowpart) {
    const int t = threadIdx.x;
    const int lane = t & 63;
    const int w = t >> 6;               // 0..3
    const int p = blockIdx.x >> 3;      // row panel 0..127
    const int e = blockIdx.x & 7;       // col eighth
    const int rb = p * 64;
    const int fr = lane & 15;
    const int rq = (lane >> 4) * 4;

    const char* pa = zt + (size_t)(p * 4) * 2048 + lane * 32;
    const int ct0 = e * 64 + w * 16;    // wave's first col-tile
    const char* pb = zt + (size_t)ct0 * 2048 + lane * 32;

    i32x4 Alo[4], Ahi[4];
    #pragma unroll
    for (int m = 0; m < 4; ++m) {
        asm volatile("global_load_dwordx4 %0, %1, off"
                     : "=v"(Alo[m]) : "v"(pa + (size_t)m * 2048));
        asm volatile("global_load_dwordx4 %0, %1, off offset:16"
                     : "=v"(Ahi[m]) : "v"(pa + (size_t)m * 2048));
    }
    i32x4 Blo[2][2], Bhi[2][2];
    #pragma unroll
    for (int n = 0; n < 2; ++n) {
        asm volatile("global_load_dwordx4 %0, %1, off"
                     : "=v"(Blo[0][n]) : "v"(pb + (size_t)n * 2048));
        asm volatile("global_load_dwordx4 %0, %1, off offset:16"
                     : "=v"(Bhi[0][n]) : "v"(pb + (size_t)n * 2048));
    }
    asm volatile("s_waitcnt vmcnt(4)" ::: "memory");    // A complete; B0 in flight
    __builtin_amdgcn_sched_barrier(0);
    i32x8 A8[4];
    #pragma unroll
    for (int m = 0; m < 4; ++m)
        A8[m] = __builtin_shufflevector(Alo[m], Ahi[m], 0, 1, 2, 3, 4, 5, 6, 7);

    float ps[4][4] = {};
    #pragma unroll
    for (int s = 0; s < 8; ++s) {
        if (s < 7) {                    // prefetch step s+1 into other buffer
            const char* pn = pb + (size_t)(s + 1) * 4096;
            #pragma unroll
            for (int n = 0; n < 2; ++n) {
                asm volatile("global_load_dwordx4 %0, %1, off"
                             : "=v"(Blo[(s + 1) & 1][n]) : "v"(pn + (size_t)n * 2048));
                asm volatile("global_load_dwordx4 %0, %1, off offset:16"
                             : "=v"(Bhi[(s + 1) & 1][n]) : "v"(pn + (size_t)n * 2048));
            }
            asm volatile("s_waitcnt vmcnt(4)" ::: "memory");  // step s done, s+1 flying
        } else {
            asm volatile("s_waitcnt vmcnt(0)" ::: "memory");
        }
        __builtin_amdgcn_sched_barrier(0);                    // rule #18 fence

        f32x4 acc[4][2] = {};
        __builtin_amdgcn_s_setprio(1);
        #pragma unroll
        for (int n = 0; n < 2; ++n) {
            i32x8 B8 = __builtin_shufflevector(Blo[s & 1][n], Bhi[s & 1][n],
                                               0, 1, 2, 3, 4, 5, 6, 7);
            #pragma unroll
            for (int m = 0; m < 4; ++m)
                acc[m][n] = __builtin_amdgcn_mfma_scale_f32_16x16x128_f8f6f4(
                    A8[m], B8, acc[m][n], 0, 0,          // cbsz=fp8, blgp=fp8
                    0, 0x7f7f7f7f, 0, 0x7f7f7f7f);       // unit scales (e8m0=127)
        }
        __builtin_amdgcn_s_setprio(0);

        const int cb = e * 1024 + w * 256 + s * 32;
        if (cb == rb || cb == rb + 32)
            accum_step<true >(acc, ps, rb, cb, rq, fr);
        else
            accum_step<false>(acc, ps, rb, cb, rq, fr);
    }

    // 16-lane reduce per row, cross-wave LDS reduce, plain store (no atomics)
    #pragma unroll
    for (int m = 0; m < 4; ++m)
        #pragma unroll
        for (int j = 0; j < 4; ++j) {
            float v = ps[m][j];
            #pragma unroll
            for (int d = 1; d < 16; d <<= 1) v += __shfl_xor(v, d);
            ps[m][j] = v;
        }
    __shared__ float red[4][64];
    if (fr == 0) {
        #pragma unroll
        for (int m = 0; m < 4; ++m)
            #pragma unroll
            for (int j = 0; j < 4; ++j)
                red[w][m * 16 + rq + j] = ps[m][j];
    }
    __syncthreads();
    if (t < 64) {
        float ssum = red[0][t] + red[1][t] + red[2][t] + red[3][t];
        rowpart[e * N2 + rb + t] = ssum;
    }
}

// --- 3. finalize: loss = (sum log(denom) - 4*sum(pos)) / (2B*5) --------------
__global__ void finalize_k(const float* __restrict__ rowpart,
                           const float* __restrict__ pospart,
                           float* __restrict__ out) {
    const int t = threadIdx.x;
    float acc = 0.f;
    for (int r = t; r < N2; r += 1024) {
        float d = 0.f;
        #pragma unroll
        for (int k = 0; k < 8; ++k) d += rowpart[k * N2 + r];
        acc += __builtin_amdgcn_logf(d);          // log2, native
    }
    acc *= 0.6931471805599453f;                   // ln2
    if (t < 256) acc -= 4.0f * pospart[t];
    #pragma unroll
    for (int m = 32; m; m >>= 1) acc += __shfl_xor(acc, m);
    __shared__ float red[16];
    if ((t & 63) == 0) red[t >> 6] = acc;
    __syncthreads();
    if (t == 0) {
        float x = 0.f;
        #pragma unroll
        for (int i = 0; i < 16; ++i) x += red[i];
        out[0] = x / (float)(2 * B_ROWS * 5);
    }
}

extern "C" void kernel_launch(void* const* d_in, const int* in_sizes, int n_in,
                              void* d_out, int out_size, void* d_ws, size_t ws_size,
                              hipStream_t stream) {
    const float* emb_i = (const float*)d_in[0];
    const float* emb_j = (const float*)d_in[1];
    i64* zt        = (i64*)d_ws;                                   // 1 MB tiled fp8
    float* rowpart = (float*)((char*)d_ws + (size_t)N2 * DIMN);    // 256 KB (8 parts)
    float* pospart = rowpart + 8 * N2;                             // 1 KB

    normpos_k<<<256, 256, 0, stream>>>(emb_i, emb_j, zt, pospart);
    gram_k<<<1024, 256, 0, stream>>>((const char*)zt, rowpart);
    finalize_k<<<1, 1024, 0, stream>>>(rowpart, pospart, (float*)d_out);
}